// Round 13
// baseline (201.375 us; speedup 1.0000x reference)
//
#include <hip/hip_runtime.h>
#include <hip/hip_bf16.h>

// MHA: B=2 S=2048 D=768 H=12 DK=64. fp32 in/out; bf16 MFMA internally.
#define B_  2
#define S_  2048
#define D_  768
#define H_  12
#define DK_ 64
#define NX_ (B_*S_*D_)      // 3145728 activation elements
#define NW_ (D_*D_)         // 589824 weight elements
#define CSC 0.18033688011112042f   // 0.125 * log2(e), baked into wq/bq

typedef __attribute__((ext_vector_type(8))) short  bf16x8;
typedef __attribute__((ext_vector_type(4))) float  f32x4;

__device__ __forceinline__ unsigned short f2bf(float f) {
    unsigned int u = __float_as_uint(f);
    u += 0x7fffu + ((u >> 16) & 1u);   // RNE
    return (unsigned short)(u >> 16);
}

// pack two fp32 -> {lo: bf16(a), hi: bf16(b)} in ONE VALU op (RNE)
__device__ __forceinline__ unsigned cvtpk(float a, float b) {
    unsigned r;
    asm("v_cvt_pk_bf16_f32 %0, %1, %2" : "=v"(r) : "v"(a), "v"(b));
    return r;
}

__device__ __forceinline__ void async_cp16(const unsigned short* g,
                                           const unsigned short* lds_uniform_base) {
    __builtin_amdgcn_global_load_lds(
        (const __attribute__((address_space(1))) unsigned int*)(uintptr_t)g,
        (__attribute__((address_space(3))) unsigned int*)(unsigned int)(uintptr_t)lds_uniform_base,
        16, 0, 0);
}

// ---------------------------------------------------------------------------
// Fused fp32->bf16 cvt, xor-swizzled per 64-el k-block (group g8 -> g8^(n&7)).
// 16 elements/thread. 1D grid: 3*768 activation blocks + 4*144 weight blocks.
// Separate pass is DELIBERATE (R9 lesson): converting once at HBM rate and
// letting gemm_qkv re-read bf16 (half-width) from L2/L3 beats fusing the
// cvt into qkv's lockstep staging loop (8.9% MFMA / 8.4% VALU = pure stall).
// ---------------------------------------------------------------------------
struct CvtArgs { const float* s[7]; };

__global__ __launch_bounds__(256) void cvt_all(CvtArgs a,
                                               unsigned short* __restrict__ Xsw,
                                               unsigned short* __restrict__ Wsw) {
    const int bx = blockIdx.x;
    int y, inner;
    if (bx < 2304) { y = bx / 768;             inner = bx % 768; }
    else           { y = 3 + (bx - 2304) / 144; inner = (bx - 2304) % 144; }
    const int idx = inner * 256 + threadIdx.x;
    const int n  = idx / 48;
    const int g2 = idx % 48;                  // 16-el group in row
    const float* src = a.s[y] + (long)n * D_ + g2 * 16;
    const float zs = (y == 3) ? CSC : 1.0f;
    unsigned short o[16];
#pragma unroll
    for (int i = 0; i < 4; i++) {
        const float4 f = *(const float4*)(src + i * 4);
        o[i*4+0] = f2bf(f.x*zs); o[i*4+1] = f2bf(f.y*zs);
        o[i*4+2] = f2bf(f.z*zs); o[i*4+3] = f2bf(f.w*zs);
    }
    unsigned short* dst = (y >= 3) ? (Wsw + (long)(y - 3) * NW_ + (long)n * D_)
                                   : (Xsw + (long)y * NX_ + (long)n * D_);
    const int key = n & 7;
#pragma unroll
    for (int h = 0; h < 2; h++) {
        const int g8 = g2 * 2 + h;
        const int kdst = (g8 >> 3) * 64 + (((g8 & 7) ^ key) * 8);
        *(uint4*)(dst + kdst) = *(const uint4*)&o[h * 8];
    }
}

// ---------------------------------------------------------------------------
// Fused QKV projection, DOUBLE-BUFFERED DMA (proven R12): issue step k+1's
// global_load_lds right after the barrier of step k into the other buffer ->
// one barrier/step, full compute phase for the DMA to land. Tile 128x64,
// grid (32,36) = 1152 blocks, dbuf 48 KB = 3 blocks/CU. nb = head.
// Outputs (globally PRE-SWIZZLED for attn's global_load_lds staging):
//   Q/K [bh][s][dk] with 16B chunk i stored at i^(s&7)   (within each row)
//   V^T [bh][dk][s] with columns PV-SLOT-permuted within each 64-block:
//     key k=s16*16+quad*4+r stored at slot (s16>>1)*32 + quad*8 + (s16&1)*4+r
//     (matches attn's in-register-P A-fragment labeling), chunk i of each
//     aligned 64-col window stored at i^(dk&7).
// ---------------------------------------------------------------------------
struct QkvArgs { const float* bias[3]; unsigned short* out[3]; };

__global__ __launch_bounds__(256, 3) void gemm_qkv(QkvArgs args,
                                                   const unsigned short* __restrict__ Xsw,
                                                   const unsigned short* __restrict__ Wsw) {
    __shared__ __align__(16) unsigned short smem[24576];   // 2 x (As 8192 + Bs 4096) shorts
    const int t    = threadIdx.x;
    const int wave = t >> 6;
    const int lane = t & 63;
    const int l16  = lane & 15;
    const int quad = lane >> 4;
    const int wm   = wave >> 1, wn = wave & 1;
    const int m0   = blockIdx.x * 128;
    const int zz   = blockIdx.y / 12;
    const int nb   = blockIdx.y % 12;
    const int n0   = nb * 64;

    const unsigned short* Ap = Xsw + (long)zz * NX_;
    const unsigned short* Wp = Wsw + (long)zz * NW_;

    f32x4 acc[4][2];
#pragma unroll
    for (int s = 0; s < 4; s++)
#pragma unroll
        for (int j = 0; j < 2; j++) acc[s][j] = (f32x4){0.f, 0.f, 0.f, 0.f};

    const int lrow = lane >> 3;
    const int lcg  = lane & 7;

    // prologue: stage k-step 0 into buffer 0
#pragma unroll
    for (int i = 0; i < 4; i++) {
        const int chunk = wave * 4 + i;            // 16 chunks: A rows
        async_cp16(Ap + (long)(m0 + chunk * 8 + lrow) * D_ + lcg * 8,
                   smem + chunk * 512);
    }
#pragma unroll
    for (int i = 0; i < 2; i++) {
        const int chunk = wave * 2 + i;            // 8 chunks: B rows
        async_cp16(Wp + (long)(n0 + chunk * 8 + lrow) * D_ + lcg * 8,
                   smem + 8192 + chunk * 512);
    }

    for (int it = 0; it < 12; ++it) {
        const int co = (it & 1) * 12288;           // current buffer
        const int no = 12288 - co;                 // next buffer
        __syncthreads();                           // step-it DMA landed + prev reads done
        if (it < 11) {                             // issue next step into other buffer
            const int k1 = (it + 1) * 64;
#pragma unroll
            for (int i = 0; i < 4; i++) {
                const int chunk = wave * 4 + i;
                async_cp16(Ap + (long)(m0 + chunk * 8 + lrow) * D_ + k1 + lcg * 8,
                           smem + no + chunk * 512);
            }
#pragma unroll
            for (int i = 0; i < 2; i++) {
                const int chunk = wave * 2 + i;
                async_cp16(Wp + (long)(n0 + chunk * 8 + lrow) * D_ + k1 + lcg * 8,
                           smem + no + 8192 + chunk * 512);
            }
        }
        const unsigned short* As = smem + co;      // [128][64] swizzled
        const unsigned short* Bs = smem + co + 8192; // [64][64] swizzled
#pragma unroll
        for (int ks = 0; ks < 2; ks++) {
            const int cg = ks * 4 + quad;
            bf16x8 af[4], bf[2];
#pragma unroll
            for (int s = 0; s < 4; s++) {
                const int r = wm * 64 + s * 16 + l16;
                af[s] = *(const bf16x8*)&As[r * 64 + ((cg ^ (r & 7)) * 8)];
            }
#pragma unroll
            for (int j = 0; j < 2; j++) {
                const int r = wn * 32 + j * 16 + l16;
                bf[j] = *(const bf16x8*)&Bs[r * 64 + ((cg ^ (r & 7)) * 8)];
            }
#pragma unroll
            for (int s = 0; s < 4; s++)
#pragma unroll
                for (int j = 0; j < 2; j++)
                    acc[s][j] = __builtin_amdgcn_mfma_f32_16x16x32_bf16(af[s], bf[j], acc[s][j], 0, 0, 0);
        }
    }
    __syncthreads();

    const int b     = m0 >> 11;
    const int sbase = m0 & (S_ - 1);
    const float zs  = (zz == 0) ? CSC : 1.0f;
    float bv[2];
#pragma unroll
    for (int j = 0; j < 2; j++) bv[j] = args.bias[zz][n0 + wn * 32 + j * 16 + l16] * zs;

    if (zz < 2) {
        unsigned short* Ls = smem;       // [128][72]
#pragma unroll
        for (int s = 0; s < 4; s++)
#pragma unroll
            for (int j = 0; j < 2; j++)
#pragma unroll
                for (int r = 0; r < 4; r++)
                    Ls[(wm * 64 + s * 16 + quad * 4 + r) * 72 + wn * 32 + j * 16 + l16] =
                        f2bf(acc[s][j][r] + bv[j]);
        __syncthreads();
        const int row  = t >> 1;
        const int half = t & 1;
        unsigned short* Op = args.out[zz];
#pragma unroll
        for (int i = 0; i < 4; i++) {
            const int col = half * 32 + i * 8;
            const int cih = col >> 3;                 // chunk within head (0..7)
            const uint4 v = *(const uint4*)&Ls[row * 72 + col];
            // global pre-swizzle: chunk cih at cih^(s&7); s = sbase+row, sbase%128==0
            *(uint4*)(Op + ((long)(b * H_ + nb) * S_ + sbase + row) * DK_
                         + ((cih ^ (row & 7)) * 8)) = v;
        }
    } else {
        unsigned short* Ls = smem;       // [64][136]: dk x pos
#pragma unroll
        for (int s = 0; s < 4; s++)
#pragma unroll
            for (int j = 0; j < 2; j++)
#pragma unroll
                for (int r = 0; r < 4; r++) {
                    const int dk  = wn * 32 + j * 16 + l16;   // 0..63
                    // PV-slot permute: key s*16+quad*4+r -> slot
                    const int pos = wm * 64 + (s >> 1) * 32 + quad * 8 + (s & 1) * 4 + r;
                    Ls[dk * 136 + pos] = f2bf(acc[s][j][r] + bv[j]);
                }
        __syncthreads();
        unsigned short* Op = args.out[2];
#pragma unroll
        for (int e = 0; e < 4; e++) {
            const int idx = e * 256 + t;              // 0..1023
            const int dk  = idx >> 4;                 // 0..63
            const int c   = idx & 15;                 // chunk across 128 pos
            const uint4 v = *(const uint4*)&Ls[dk * 136 + c * 8];
            // global pre-swizzle: within aligned 64-window, chunk i at i^(dk&7)
            *(uint4*)(Op + ((long)(b * H_ + nb) * DK_ + dk) * S_
                         + sbase + (c >> 3) * 64 + (((c & 7) ^ (dk & 7)) * 8)) = v;
        }
    }
}

// ---------------------------------------------------------------------------
// Flash attention v9: v8 structure (DMA staging, 64-row q-tiles, 4 waves x 16
// rows, 768 blocks = 3/CU = 12 waves/CU, swizzled conflict-free tiles,
// 1 barrier/iter, XCD-local bh=bid%24, in-register P via swapped QK^T) with
// the softmax ROW-SUM MOVED TO THE MFMA PIPE: lacc = mfma(pf, ones, lacc).
// pf is A[m=query][k=key-slot], so D[m=q][n] has every column = lsum(q);
// the lane holds rows q = quad*4+r at col n = l16 -> lacc[r] = lsum(quad*4+r)
// = EXACTLY the scl[r] index the epilogue needs. Deletes 16 v_add_f32/iter
// (VALU was 52% busy vs MFMA 19%) + all end-of-loop shuffles; adds 2 MFMA/iter
// on the idle matrix pipe. Normalization now uses the sum of the bf16-rounded
// P actually fed to PV (more self-consistent).
// ---------------------------------------------------------------------------
__global__ __launch_bounds__(256, 3) void attn_kernel(
    const unsigned short* __restrict__ Q, const unsigned short* __restrict__ K,
    const unsigned short* __restrict__ Vt, unsigned short* __restrict__ Ao)
{
    const int t    = threadIdx.x;
    const int wave = t >> 6;
    const int lane = t & 63;
    const int l16  = lane & 15;
    const int quad = lane >> 4;
    const int bid  = blockIdx.x;        // 768 blocks, 1D
    const int bh    = bid % 24;         // XCD = bid % 8 -> head-local L2
    const int qtile = bid / 24;         // 32 tiles of 64 rows

    const unsigned short* Qp = Q  + (long)bh * S_ * DK_;
    const unsigned short* Kp = K  + (long)bh * S_ * DK_;
    const unsigned short* Vp = Vt + (long)bh * DK_ * S_;

    __shared__ __align__(16) unsigned short smem[16384];   // 32 KB: K dbuf + V dbuf

    // swizzle keys for fragment reads (row = *16 + l16 -> key = l16&7)
    const int fkey = l16 & 7;
    const int fo0  = ((quad ^ fkey) * 8);            // ks=0 chunk
    const int fo1  = (((4 + quad) ^ fkey) * 8);      // ks=1 chunk

    // Q fragments (global is pre-swizzled: chunk c at c^(s&7); key == fkey)
    bf16x8 qfrag[2];
    {
        const long qoff = (long)(qtile * 64 + wave * 16 + l16) * DK_;
        qfrag[0] = *(const bf16x8*)(Qp + qoff + fo0);
        qfrag[1] = *(const bf16x8*)(Qp + qoff + fo1);
    }

    // ones B-operand for the MFMA row-sum (bf16 1.0 = 0x3F80)
    const uint4 onesw = {0x3F803F80u, 0x3F803F80u, 0x3F803F80u, 0x3F803F80u};
    const bf16x8 vones = *(const bf16x8*)&onesw;

    // async staging: per wave 2 K-calls + 2 V-calls of 1 KB each (linear src).
    const int ci0 = wave * 2;                        // 0,2,4,6
    const int kd0 = ci0 * 512;                       // LDS short offset of call 0
    const unsigned short* gk  = Kp + ci0 * 512 + lane * 8;
    const unsigned short* gv0 = Vp + (long)(ci0 * 8 + (lane >> 3)) * S_ + (lane & 7) * 8;
    const unsigned short* gv1 = gv0 + 8 * S_;

    // prologue: stage tile 0 into buffer 0
    async_cp16(gk,        smem + kd0);
    async_cp16(gk + 512,  smem + kd0 + 512);
    async_cp16(gv0,       smem + 8192 + kd0);
    async_cp16(gv1,       smem + 8192 + kd0 + 512);
    gk += 4096;  gv0 += 64;  gv1 += 64;

    f32x4 oacc[4];
#pragma unroll
    for (int j = 0; j < 4; j++) oacc[j] = (f32x4){0.f, 0.f, 0.f, 0.f};
    f32x4 lacc = (f32x4){0.f, 0.f, 0.f, 0.f};

    for (int it = 0; it < 32; ++it) {
        const int co = (it & 1) * 4096;          // current buffer offset
        const int no = 4096 - co;                // next buffer offset
        __syncthreads();                 // staging landed + prev reads done
        const unsigned short* Ks = smem + co;
        const unsigned short* Vs = smem + 8192 + co;

        if (it < 31) {                   // issue next-tile DMA into other buffer
            async_cp16(gk,        smem + no + kd0);
            async_cp16(gk + 512,  smem + no + kd0 + 512);
            async_cp16(gv0,       smem + 8192 + no + kd0);
            async_cp16(gv1,       smem + 8192 + no + kd0 + 512);
            gk += 4096;  gv0 += 64;  gv1 += 64;
        }

        // S^T = K Q^T (swapped args): sacc[j] -> S[key=j*16+quad*4+r][q=l16]
        f32x4 sacc[4];
#pragma unroll
        for (int j = 0; j < 4; j++) sacc[j] = (f32x4){0.f, 0.f, 0.f, 0.f};
#pragma unroll
        for (int ks = 0; ks < 2; ks++) {
            const int fo = ks ? fo1 : fo0;
            const bf16x8 qf = ks ? qfrag[1] : qfrag[0];
#pragma unroll
            for (int j = 0; j < 4; j++) {
                const bf16x8 bf = *(const bf16x8*)&Ks[(j * 16 + l16) * 64 + fo];
                sacc[j] = __builtin_amdgcn_mfma_f32_16x16x32_bf16(bf, qf, sacc[j], 0, 0, 0);
            }
        }

        // p = exp2(s); in-register PV A-fragments (no LDS, no cross-lane)
        float p[4][4];
#pragma unroll
        for (int j = 0; j < 4; j++)
#pragma unroll
            for (int r = 0; r < 4; r++)
                p[j][r] = exp2f(sacc[j][r]);
        uint4 pw0, pw1;
        pw0.x = cvtpk(p[0][0], p[0][1]);  pw0.y = cvtpk(p[0][2], p[0][3]);
        pw0.z = cvtpk(p[1][0], p[1][1]);  pw0.w = cvtpk(p[1][2], p[1][3]);
        pw1.x = cvtpk(p[2][0], p[2][1]);  pw1.y = cvtpk(p[2][2], p[2][3]);
        pw1.z = cvtpk(p[3][0], p[3][1]);  pw1.w = cvtpk(p[3][2], p[3][3]);
        const bf16x8 pf0 = *(const bf16x8*)&pw0;
        const bf16x8 pf1 = *(const bf16x8*)&pw1;

        // row-sum on the MFMA pipe: lacc[r] += sum_k P[k][q=quad*4+r]
        lacc = __builtin_amdgcn_mfma_f32_16x16x32_bf16(pf0, vones, lacc, 0, 0, 0);
        lacc = __builtin_amdgcn_mfma_f32_16x16x32_bf16(pf1, vones, lacc, 0, 0, 0);

        // O += P V : A = in-register P, B = V^T tile (PV-slot-permuted cols)
#pragma unroll
        for (int ks = 0; ks < 2; ks++) {
            const int fo = ks ? fo1 : fo0;
            const bf16x8 pf = ks ? pf1 : pf0;
#pragma unroll
            for (int j = 0; j < 4; j++) {
                const bf16x8 vf = *(const bf16x8*)&Vs[(j * 16 + l16) * 64 + fo];
                oacc[j] = __builtin_amdgcn_mfma_f32_16x16x32_bf16(pf, vf, oacc[j], 0, 0, 0);
            }
        }
    }

    // lacc[r] = lsum(q = quad*4+r) directly: no shuffles needed.
    float scl[4];
#pragma unroll
    for (int r = 0; r < 4; r++) scl[r] = 1.f / lacc[r];

    // epilogue: bf16 O into scratch (swizzled), then straight physical copy.
    __syncthreads();
    unsigned short* Sc = smem;           // [64][64] swizzled scratch
#pragma unroll
    for (int j = 0; j < 4; j++)
#pragma unroll
        for (int r = 0; r < 4; r++) {
            const int row = wave * 16 + quad * 4 + r;
            const int c   = j * 2 + (l16 >> 3);
            Sc[row * 64 + ((c ^ (row & 7)) * 8) + (l16 & 7)] =
                f2bf(oacc[j][r] * scl[r]);
        }

    const int b = bh / H_, h = bh % H_;
    const int row = t >> 2;             // wave-local rows: no barrier needed
    const int p0  = (t & 3) * 2;
    const int qrow = qtile * 64 + row;
    unsigned short* dst = Ao + (long)(b * S_ + qrow) * D_ + h * DK_;
    *(uint4*)(dst + p0 * 8)       = *(const uint4*)&Sc[row * 64 + p0 * 8];
    *(uint4*)(dst + (p0 + 1) * 8) = *(const uint4*)&Sc[row * 64 + (p0 + 1) * 8];
}

// ---------------------------------------------------------------------------
// Output projection, DOUBLE-BUFFERED DMA (proven R12): issue step k+1 right
// after step k's barrier -> one barrier/step, latency hidden. Tile 64x64,
// grid (64,12)=768 = 3/CU; dbuf 32 KB, launch_bounds(256,4). 4 waves 2x2.
// ---------------------------------------------------------------------------
__global__ __launch_bounds__(256, 4) void gemm_out(
    const unsigned short* __restrict__ A, const unsigned short* __restrict__ Wsw,
    const float* __restrict__ bias, float* __restrict__ Out)
{
    __shared__ __align__(16) unsigned short smem[16384];   // 2 x (As 4096 + Bs 4096) shorts

    const int t    = threadIdx.x;
    const int wave = t >> 6;
    const int lane = t & 63;
    const int l16  = lane & 15;
    const int quad = lane >> 4;
    const int wm   = wave >> 1, wn = wave & 1;
    const int m0   = blockIdx.x * 64;
    const int n0   = blockIdx.y * 64;

    f32x4 acc[2][2];
#pragma unroll
    for (int s = 0; s < 2; s++)
#pragma unroll
        for (int j = 0; j < 2; j++) acc[s][j] = (f32x4){0.f, 0.f, 0.f, 0.f};

    const int lrow = lane >> 3;
    const int lcg  = lane & 7;

    // prologue: stage k-step 0 into buffer 0
#pragma unroll
    for (int i = 0; i < 2; i++) {
        const int chunk = wave * 2 + i;
        async_cp16(A + (long)(m0 + chunk * 8 + lrow) * D_ + lcg * 8,
                   smem + chunk * 512);
        async_cp16(Wsw + (long)(n0 + chunk * 8 + lrow) * D_ + lcg * 8,
                   smem + 4096 + chunk * 512);
    }

    for (int it = 0; it < 12; ++it) {
        const int co = (it & 1) * 8192;
        const int no = 8192 - co;
        __syncthreads();                           // step-it DMA landed + prev reads done
        if (it < 11) {
            const int k1 = (it + 1) * 64;
#pragma unroll
            for (int i = 0; i < 2; i++) {
                const int chunk = wave * 2 + i;
                async_cp16(A + (long)(m0 + chunk * 8 + lrow) * D_ + k1 + lcg * 8,
                           smem + no + chunk * 512);
                async_cp16(Wsw + (long)(n0 + chunk * 8 + lrow) * D_ + k1 + lcg * 8,
                           smem + no + 4096 + chunk * 512);
            }
        }
        const unsigned short* As = smem + co;
        const unsigned short* Bs = smem + co + 4096;
#pragma unroll
        for (int ks = 0; ks < 2; ks++) {
            const int cg = ks * 4 + quad;
            bf16x8 af[2], bf[2];
#pragma unroll
            for (int s = 0; s < 2; s++) {
                const int r = wm * 32 + s * 16 + l16;
                af[s] = *(const bf16x8*)&As[r * 64 + ((cg ^ (r & 7)) * 8)];
            }
#pragma unroll
            for (int j = 0; j < 2; j++) {
                const int r = wn * 32 + j * 16 + l16;
                bf[j] = *(const bf16x8*)&Bs[r * 64 + ((cg ^ (r & 7)) * 8)];
            }
#pragma unroll
            for (int s = 0; s < 2; s++)
#pragma unroll
                for (int j = 0; j < 2; j++)
                    acc[s][j] = __builtin_amdgcn_mfma_f32_16x16x32_bf16(af[s], bf[j], acc[s][j], 0, 0, 0);
        }
    }

    float bv[2];
#pragma unroll
    for (int j = 0; j < 2; j++) bv[j] = bias[n0 + wn * 32 + j * 16 + l16];

    __syncthreads();                     // done with As/Bs before reuse
    float* fl = (float*)smem;            // [64][67]
#pragma unroll
    for (int s = 0; s < 2; s++)
#pragma unroll
        for (int j = 0; j < 2; j++)
#pragma unroll
            for (int r = 0; r < 4; r++)
                fl[(wm * 32 + s * 16 + quad * 4 + r) * 67 + wn * 32 + j * 16 + l16] =
                    acc[s][j][r] + bv[j];
    __syncthreads();
    const int row = t >> 2, c0 = (t & 3) * 16;
#pragma unroll
    for (int i = 0; i < 4; i++) {
        const float4 v = *(const float4*)&fl[row * 67 + c0 + i * 4];
        *(float4*)(Out + (long)(m0 + row) * D_ + n0 + c0 + i * 4) = v;
    }
}

extern "C" void kernel_launch(void* const* d_in, const int* in_sizes, int n_in,
                              void* d_out, int out_size, void* d_ws, size_t ws_size,
                              hipStream_t stream) {
    const float* k_in = (const float*)d_in[0];
    const float* q_in = (const float*)d_in[1];
    const float* v_in = (const float*)d_in[2];
    // d_in[3] = mask: no-op per reference
    const float* wq = (const float*)d_in[4];
    const float* bq = (const float*)d_in[5];
    const float* wk = (const float*)d_in[6];
    const float* bk = (const float*)d_in[7];
    const float* wv = (const float*)d_in[8];
    const float* bv = (const float*)d_in[9];
    const float* wo = (const float*)d_in[10];
    const float* bo = (const float*)d_in[11];

    unsigned short* ws = (unsigned short*)d_ws;
    unsigned short* Wsw = ws;                          // 4*NW bf16 swizzled
    unsigned short* Qb  = Wsw + 4ll * NW_;             // NX bf16
    unsigned short* Kb  = Qb + (long)NX_;
    unsigned short* Vt  = Kb + (long)NX_;
    unsigned short* Xsw = Vt + (long)NX_;              // 3*NX (dead after qkv)
    unsigned short* Ao  = Xsw;                         // aliases Xsw

    CvtArgs ca;
    ca.s[0] = q_in; ca.s[1] = k_in; ca.s[2] = v_in;
    ca.s[3] = wq;   ca.s[4] = wk;   ca.s[5] = wv;  ca.s[6] = wo;
    cvt_all<<<dim3(2880), 256, 0, stream>>>(ca, Xsw, Wsw);

    QkvArgs qa;
    qa.bias[0] = bq; qa.bias[1] = bk; qa.bias[2] = bv;
    qa.out[0] = Qb;  qa.out[1] = Kb;  qa.out[2] = Vt;
    gemm_qkv<<<dim3(32, 36), 256, 0, stream>>>(qa, Xsw, Wsw);

    attn_kernel<<<dim3(768), 256, 0, stream>>>(Qb, Kb, Vt, Ao);

    gemm_out<<<dim3(64, 12), 256, 0, stream>>>(Ao, Wsw + 3ll * NW_, bo, (float*)d_out);
}

// Round 14
// 200.257 us; speedup vs baseline: 1.0056x; 1.0056x over previous
//
#include <hip/hip_runtime.h>
#include <hip/hip_bf16.h>

// MHA: B=2 S=2048 D=768 H=12 DK=64. fp32 in/out; bf16 MFMA internally.
#define B_  2
#define S_  2048
#define D_  768
#define H_  12
#define DK_ 64
#define NX_ (B_*S_*D_)      // 3145728 activation elements
#define NW_ (D_*D_)         // 589824 weight elements
#define CSC 0.18033688011112042f   // 0.125 * log2(e), baked into wq/bq

typedef __attribute__((ext_vector_type(8))) short  bf16x8;
typedef __attribute__((ext_vector_type(4))) float  f32x4;

__device__ __forceinline__ unsigned short f2bf(float f) {
    unsigned int u = __float_as_uint(f);
    u += 0x7fffu + ((u >> 16) & 1u);   // RNE
    return (unsigned short)(u >> 16);
}

// pack two fp32 -> {lo: bf16(a), hi: bf16(b)} in ONE VALU op (RNE)
__device__ __forceinline__ unsigned cvtpk(float a, float b) {
    unsigned r;
    asm("v_cvt_pk_bf16_f32 %0, %1, %2" : "=v"(r) : "v"(a), "v"(b));
    return r;
}

__device__ __forceinline__ void async_cp16(const unsigned short* g,
                                           const unsigned short* lds_uniform_base) {
    __builtin_amdgcn_global_load_lds(
        (const __attribute__((address_space(1))) unsigned int*)(uintptr_t)g,
        (__attribute__((address_space(3))) unsigned int*)(unsigned int)(uintptr_t)lds_uniform_base,
        16, 0, 0);
}

// ---------------------------------------------------------------------------
// Fused fp32->bf16 cvt, xor-swizzled per 64-el k-block (group g8 -> g8^(n&7)).
// 16 elements/thread. 1D grid: 3*768 activation blocks + 4*144 weight blocks.
// Separate pass is DELIBERATE (R9 lesson): converting once at HBM rate and
// letting gemm_qkv re-read bf16 (half-width) from L2/L3 beats fusing the
// cvt into qkv's lockstep staging loop (8.9% MFMA / 8.4% VALU = pure stall).
// ---------------------------------------------------------------------------
struct CvtArgs { const float* s[7]; };

__global__ __launch_bounds__(256) void cvt_all(CvtArgs a,
                                               unsigned short* __restrict__ Xsw,
                                               unsigned short* __restrict__ Wsw) {
    const int bx = blockIdx.x;
    int y, inner;
    if (bx < 2304) { y = bx / 768;             inner = bx % 768; }
    else           { y = 3 + (bx - 2304) / 144; inner = (bx - 2304) % 144; }
    const int idx = inner * 256 + threadIdx.x;
    const int n  = idx / 48;
    const int g2 = idx % 48;                  // 16-el group in row
    const float* src = a.s[y] + (long)n * D_ + g2 * 16;
    const float zs = (y == 3) ? CSC : 1.0f;
    unsigned short o[16];
#pragma unroll
    for (int i = 0; i < 4; i++) {
        const float4 f = *(const float4*)(src + i * 4);
        o[i*4+0] = f2bf(f.x*zs); o[i*4+1] = f2bf(f.y*zs);
        o[i*4+2] = f2bf(f.z*zs); o[i*4+3] = f2bf(f.w*zs);
    }
    unsigned short* dst = (y >= 3) ? (Wsw + (long)(y - 3) * NW_ + (long)n * D_)
                                   : (Xsw + (long)y * NX_ + (long)n * D_);
    const int key = n & 7;
#pragma unroll
    for (int h = 0; h < 2; h++) {
        const int g8 = g2 * 2 + h;
        const int kdst = (g8 >> 3) * 64 + (((g8 & 7) ^ key) * 8);
        *(uint4*)(dst + kdst) = *(const uint4*)&o[h * 8];
    }
}

// ---------------------------------------------------------------------------
// Fused QKV projection, DOUBLE-BUFFERED DMA (proven R12): issue step k+1's
// global_load_lds right after the barrier of step k into the other buffer ->
// one barrier/step, full compute phase for the DMA to land. Tile 128x64,
// grid (32,36) = 1152 blocks, dbuf 48 KB = 3 blocks/CU. nb = head.
// Outputs (globally PRE-SWIZZLED for attn's global_load_lds staging):
//   Q/K [bh][s][dk] with 16B chunk i stored at i^(s&7)   (within each row)
//   V^T [bh][dk][s] with columns PV-SLOT-permuted within each 64-block:
//     key k=s16*16+quad*4+r stored at slot (s16>>1)*32 + quad*8 + (s16&1)*4+r
//     (matches attn's in-register-P A-fragment labeling), chunk i of each
//     aligned 64-col window stored at i^(dk&7).
// ---------------------------------------------------------------------------
struct QkvArgs { const float* bias[3]; unsigned short* out[3]; };

__global__ __launch_bounds__(256, 3) void gemm_qkv(QkvArgs args,
                                                   const unsigned short* __restrict__ Xsw,
                                                   const unsigned short* __restrict__ Wsw) {
    __shared__ __align__(16) unsigned short smem[24576];   // 2 x (As 8192 + Bs 4096) shorts
    const int t    = threadIdx.x;
    const int wave = t >> 6;
    const int lane = t & 63;
    const int l16  = lane & 15;
    const int quad = lane >> 4;
    const int wm   = wave >> 1, wn = wave & 1;
    const int m0   = blockIdx.x * 128;
    const int zz   = blockIdx.y / 12;
    const int nb   = blockIdx.y % 12;
    const int n0   = nb * 64;

    const unsigned short* Ap = Xsw + (long)zz * NX_;
    const unsigned short* Wp = Wsw + (long)zz * NW_;

    f32x4 acc[4][2];
#pragma unroll
    for (int s = 0; s < 4; s++)
#pragma unroll
        for (int j = 0; j < 2; j++) acc[s][j] = (f32x4){0.f, 0.f, 0.f, 0.f};

    const int lrow = lane >> 3;
    const int lcg  = lane & 7;

    // prologue: stage k-step 0 into buffer 0
#pragma unroll
    for (int i = 0; i < 4; i++) {
        const int chunk = wave * 4 + i;            // 16 chunks: A rows
        async_cp16(Ap + (long)(m0 + chunk * 8 + lrow) * D_ + lcg * 8,
                   smem + chunk * 512);
    }
#pragma unroll
    for (int i = 0; i < 2; i++) {
        const int chunk = wave * 2 + i;            // 8 chunks: B rows
        async_cp16(Wp + (long)(n0 + chunk * 8 + lrow) * D_ + lcg * 8,
                   smem + 8192 + chunk * 512);
    }

    for (int it = 0; it < 12; ++it) {
        const int co = (it & 1) * 12288;           // current buffer
        const int no = 12288 - co;                 // next buffer
        __syncthreads();                           // step-it DMA landed + prev reads done
        if (it < 11) {                             // issue next step into other buffer
            const int k1 = (it + 1) * 64;
#pragma unroll
            for (int i = 0; i < 4; i++) {
                const int chunk = wave * 4 + i;
                async_cp16(Ap + (long)(m0 + chunk * 8 + lrow) * D_ + k1 + lcg * 8,
                           smem + no + chunk * 512);
            }
#pragma unroll
            for (int i = 0; i < 2; i++) {
                const int chunk = wave * 2 + i;
                async_cp16(Wp + (long)(n0 + chunk * 8 + lrow) * D_ + k1 + lcg * 8,
                           smem + no + 8192 + chunk * 512);
            }
        }
        const unsigned short* As = smem + co;      // [128][64] swizzled
        const unsigned short* Bs = smem + co + 8192; // [64][64] swizzled
#pragma unroll
        for (int ks = 0; ks < 2; ks++) {
            const int cg = ks * 4 + quad;
            bf16x8 af[4], bf[2];
#pragma unroll
            for (int s = 0; s < 4; s++) {
                const int r = wm * 64 + s * 16 + l16;
                af[s] = *(const bf16x8*)&As[r * 64 + ((cg ^ (r & 7)) * 8)];
            }
#pragma unroll
            for (int j = 0; j < 2; j++) {
                const int r = wn * 32 + j * 16 + l16;
                bf[j] = *(const bf16x8*)&Bs[r * 64 + ((cg ^ (r & 7)) * 8)];
            }
#pragma unroll
            for (int s = 0; s < 4; s++)
#pragma unroll
                for (int j = 0; j < 2; j++)
                    acc[s][j] = __builtin_amdgcn_mfma_f32_16x16x32_bf16(af[s], bf[j], acc[s][j], 0, 0, 0);
        }
    }
    __syncthreads();

    const int b     = m0 >> 11;
    const int sbase = m0 & (S_ - 1);
    const float zs  = (zz == 0) ? CSC : 1.0f;
    float bv[2];
#pragma unroll
    for (int j = 0; j < 2; j++) bv[j] = args.bias[zz][n0 + wn * 32 + j * 16 + l16] * zs;

    if (zz < 2) {
        unsigned short* Ls = smem;       // [128][72]
#pragma unroll
        for (int s = 0; s < 4; s++)
#pragma unroll
            for (int j = 0; j < 2; j++)
#pragma unroll
                for (int r = 0; r < 4; r++)
                    Ls[(wm * 64 + s * 16 + quad * 4 + r) * 72 + wn * 32 + j * 16 + l16] =
                        f2bf(acc[s][j][r] + bv[j]);
        __syncthreads();
        const int row  = t >> 1;
        const int half = t & 1;
        unsigned short* Op = args.out[zz];
#pragma unroll
        for (int i = 0; i < 4; i++) {
            const int col = half * 32 + i * 8;
            const int cih = col >> 3;                 // chunk within head (0..7)
            const uint4 v = *(const uint4*)&Ls[row * 72 + col];
            // global pre-swizzle: chunk cih at cih^(s&7); s = sbase+row, sbase%128==0
            *(uint4*)(Op + ((long)(b * H_ + nb) * S_ + sbase + row) * DK_
                         + ((cih ^ (row & 7)) * 8)) = v;
        }
    } else {
        unsigned short* Ls = smem;       // [64][136]: dk x pos
#pragma unroll
        for (int s = 0; s < 4; s++)
#pragma unroll
            for (int j = 0; j < 2; j++)
#pragma unroll
                for (int r = 0; r < 4; r++) {
                    const int dk  = wn * 32 + j * 16 + l16;   // 0..63
                    // PV-slot permute: key s*16+quad*4+r -> slot
                    const int pos = wm * 64 + (s >> 1) * 32 + quad * 8 + (s & 1) * 4 + r;
                    Ls[dk * 136 + pos] = f2bf(acc[s][j][r] + bv[j]);
                }
        __syncthreads();
        unsigned short* Op = args.out[2];
#pragma unroll
        for (int e = 0; e < 4; e++) {
            const int idx = e * 256 + t;              // 0..1023
            const int dk  = idx >> 4;                 // 0..63
            const int c   = idx & 15;                 // chunk across 128 pos
            const uint4 v = *(const uint4*)&Ls[dk * 136 + c * 8];
            // global pre-swizzle: within aligned 64-window, chunk i at i^(dk&7)
            *(uint4*)(Op + ((long)(b * H_ + nb) * DK_ + dk) * S_
                         + sbase + (c >> 3) * 64 + (((c & 7) ^ (dk & 7)) * 8)) = v;
        }
    }
}

// ---------------------------------------------------------------------------
// Flash attention v10: v9 (proven 48.4 us: DMA staging, 64-row q-tiles,
// 4 waves x 16 rows, 768 blocks = 3/CU, swizzled conflict-free tiles,
// 1 barrier/iter, XCD-local bh=bid%24, in-register P via swapped QK^T,
// MFMA-pipe row-sum) + T5 s_setprio(1) around the MFMA clusters.
// Mechanism (guide m191, attn +4-7%): waves on a SIMD come from 3
// INDEPENDENT blocks at different phases -> raising prio while this wave
// feeds the matrix pipe wins arbitration against other blocks' staging.
// exp2/cvtpk run at prio 0.
// ---------------------------------------------------------------------------
__global__ __launch_bounds__(256, 3) void attn_kernel(
    const unsigned short* __restrict__ Q, const unsigned short* __restrict__ K,
    const unsigned short* __restrict__ Vt, unsigned short* __restrict__ Ao)
{
    const int t    = threadIdx.x;
    const int wave = t >> 6;
    const int lane = t & 63;
    const int l16  = lane & 15;
    const int quad = lane >> 4;
    const int bid  = blockIdx.x;        // 768 blocks, 1D
    const int bh    = bid % 24;         // XCD = bid % 8 -> head-local L2
    const int qtile = bid / 24;         // 32 tiles of 64 rows

    const unsigned short* Qp = Q  + (long)bh * S_ * DK_;
    const unsigned short* Kp = K  + (long)bh * S_ * DK_;
    const unsigned short* Vp = Vt + (long)bh * DK_ * S_;

    __shared__ __align__(16) unsigned short smem[16384];   // 32 KB: K dbuf + V dbuf

    // swizzle keys for fragment reads (row = *16 + l16 -> key = l16&7)
    const int fkey = l16 & 7;
    const int fo0  = ((quad ^ fkey) * 8);            // ks=0 chunk
    const int fo1  = (((4 + quad) ^ fkey) * 8);      // ks=1 chunk

    // Q fragments (global is pre-swizzled: chunk c at c^(s&7); key == fkey)
    bf16x8 qfrag[2];
    {
        const long qoff = (long)(qtile * 64 + wave * 16 + l16) * DK_;
        qfrag[0] = *(const bf16x8*)(Qp + qoff + fo0);
        qfrag[1] = *(const bf16x8*)(Qp + qoff + fo1);
    }

    // ones B-operand for the MFMA row-sum (bf16 1.0 = 0x3F80)
    const uint4 onesw = {0x3F803F80u, 0x3F803F80u, 0x3F803F80u, 0x3F803F80u};
    const bf16x8 vones = *(const bf16x8*)&onesw;

    // async staging: per wave 2 K-calls + 2 V-calls of 1 KB each (linear src).
    const int ci0 = wave * 2;                        // 0,2,4,6
    const int kd0 = ci0 * 512;                       // LDS short offset of call 0
    const unsigned short* gk  = Kp + ci0 * 512 + lane * 8;
    const unsigned short* gv0 = Vp + (long)(ci0 * 8 + (lane >> 3)) * S_ + (lane & 7) * 8;
    const unsigned short* gv1 = gv0 + 8 * S_;

    // prologue: stage tile 0 into buffer 0
    async_cp16(gk,        smem + kd0);
    async_cp16(gk + 512,  smem + kd0 + 512);
    async_cp16(gv0,       smem + 8192 + kd0);
    async_cp16(gv1,       smem + 8192 + kd0 + 512);
    gk += 4096;  gv0 += 64;  gv1 += 64;

    f32x4 oacc[4];
#pragma unroll
    for (int j = 0; j < 4; j++) oacc[j] = (f32x4){0.f, 0.f, 0.f, 0.f};
    f32x4 lacc = (f32x4){0.f, 0.f, 0.f, 0.f};

    for (int it = 0; it < 32; ++it) {
        const int co = (it & 1) * 4096;          // current buffer offset
        const int no = 4096 - co;                // next buffer offset
        __syncthreads();                 // staging landed + prev reads done
        const unsigned short* Ks = smem + co;
        const unsigned short* Vs = smem + 8192 + co;

        if (it < 31) {                   // issue next-tile DMA into other buffer
            async_cp16(gk,        smem + no + kd0);
            async_cp16(gk + 512,  smem + no + kd0 + 512);
            async_cp16(gv0,       smem + 8192 + no + kd0);
            async_cp16(gv1,       smem + 8192 + no + kd0 + 512);
            gk += 4096;  gv0 += 64;  gv1 += 64;
        }

        // S^T = K Q^T (swapped args): sacc[j] -> S[key=j*16+quad*4+r][q=l16]
        f32x4 sacc[4];
#pragma unroll
        for (int j = 0; j < 4; j++) sacc[j] = (f32x4){0.f, 0.f, 0.f, 0.f};
        __builtin_amdgcn_s_setprio(1);
#pragma unroll
        for (int ks = 0; ks < 2; ks++) {
            const int fo = ks ? fo1 : fo0;
            const bf16x8 qf = ks ? qfrag[1] : qfrag[0];
#pragma unroll
            for (int j = 0; j < 4; j++) {
                const bf16x8 bf = *(const bf16x8*)&Ks[(j * 16 + l16) * 64 + fo];
                sacc[j] = __builtin_amdgcn_mfma_f32_16x16x32_bf16(bf, qf, sacc[j], 0, 0, 0);
            }
        }
        __builtin_amdgcn_s_setprio(0);

        // p = exp2(s); in-register PV A-fragments (no LDS, no cross-lane)
        float p[4][4];
#pragma unroll
        for (int j = 0; j < 4; j++)
#pragma unroll
            for (int r = 0; r < 4; r++)
                p[j][r] = exp2f(sacc[j][r]);
        uint4 pw0, pw1;
        pw0.x = cvtpk(p[0][0], p[0][1]);  pw0.y = cvtpk(p[0][2], p[0][3]);
        pw0.z = cvtpk(p[1][0], p[1][1]);  pw0.w = cvtpk(p[1][2], p[1][3]);
        pw1.x = cvtpk(p[2][0], p[2][1]);  pw1.y = cvtpk(p[2][2], p[2][3]);
        pw1.z = cvtpk(p[3][0], p[3][1]);  pw1.w = cvtpk(p[3][2], p[3][3]);
        const bf16x8 pf0 = *(const bf16x8*)&pw0;
        const bf16x8 pf1 = *(const bf16x8*)&pw1;

        __builtin_amdgcn_s_setprio(1);
        // row-sum on the MFMA pipe: lacc[r] += sum_k P[k][q=quad*4+r]
        lacc = __builtin_amdgcn_mfma_f32_16x16x32_bf16(pf0, vones, lacc, 0, 0, 0);
        lacc = __builtin_amdgcn_mfma_f32_16x16x32_bf16(pf1, vones, lacc, 0, 0, 0);

        // O += P V : A = in-register P, B = V^T tile (PV-slot-permuted cols)
#pragma unroll
        for (int ks = 0; ks < 2; ks++) {
            const int fo = ks ? fo1 : fo0;
            const bf16x8 pf = ks ? pf1 : pf0;
#pragma unroll
            for (int j = 0; j < 4; j++) {
                const bf16x8 vf = *(const bf16x8*)&Vs[(j * 16 + l16) * 64 + fo];
                oacc[j] = __builtin_amdgcn_mfma_f32_16x16x32_bf16(pf, vf, oacc[j], 0, 0, 0);
            }
        }
        __builtin_amdgcn_s_setprio(0);
    }

    // lacc[r] = lsum(q = quad*4+r) directly: no shuffles needed.
    float scl[4];
#pragma unroll
    for (int r = 0; r < 4; r++) scl[r] = 1.f / lacc[r];

    // epilogue: bf16 O into scratch (swizzled), then straight physical copy.
    __syncthreads();
    unsigned short* Sc = smem;           // [64][64] swizzled scratch
#pragma unroll
    for (int j = 0; j < 4; j++)
#pragma unroll
        for (int r = 0; r < 4; r++) {
            const int row = wave * 16 + quad * 4 + r;
            const int c   = j * 2 + (l16 >> 3);
            Sc[row * 64 + ((c ^ (row & 7)) * 8) + (l16 & 7)] =
                f2bf(oacc[j][r] * scl[r]);
        }

    const int b = bh / H_, h = bh % H_;
    const int row = t >> 2;             // wave-local rows: no barrier needed
    const int p0  = (t & 3) * 2;
    const int qrow = qtile * 64 + row;
    unsigned short* dst = Ao + (long)(b * S_ + qrow) * D_ + h * DK_;
    *(uint4*)(dst + p0 * 8)       = *(const uint4*)&Sc[row * 64 + p0 * 8];
    *(uint4*)(dst + (p0 + 1) * 8) = *(const uint4*)&Sc[row * 64 + (p0 + 1) * 8];
}

// ---------------------------------------------------------------------------
// Output projection, DOUBLE-BUFFERED DMA (proven R12): issue step k+1 right
// after step k's barrier -> one barrier/step, latency hidden. Tile 64x64,
// grid (64,12)=768 = 3/CU; dbuf 32 KB, launch_bounds(256,4). 4 waves 2x2.
// ---------------------------------------------------------------------------
__global__ __launch_bounds__(256, 4) void gemm_out(
    const unsigned short* __restrict__ A, const unsigned short* __restrict__ Wsw,
    const float* __restrict__ bias, float* __restrict__ Out)
{
    __shared__ __align__(16) unsigned short smem[16384];   // 2 x (As 4096 + Bs 4096) shorts

    const int t    = threadIdx.x;
    const int wave = t >> 6;
    const int lane = t & 63;
    const int l16  = lane & 15;
    const int quad = lane >> 4;
    const int wm   = wave >> 1, wn = wave & 1;
    const int m0   = blockIdx.x * 64;
    const int n0   = blockIdx.y * 64;

    f32x4 acc[2][2];
#pragma unroll
    for (int s = 0; s < 2; s++)
#pragma unroll
        for (int j = 0; j < 2; j++) acc[s][j] = (f32x4){0.f, 0.f, 0.f, 0.f};

    const int lrow = lane >> 3;
    const int lcg  = lane & 7;

    // prologue: stage k-step 0 into buffer 0
#pragma unroll
    for (int i = 0; i < 2; i++) {
        const int chunk = wave * 2 + i;
        async_cp16(A + (long)(m0 + chunk * 8 + lrow) * D_ + lcg * 8,
                   smem + chunk * 512);
        async_cp16(Wsw + (long)(n0 + chunk * 8 + lrow) * D_ + lcg * 8,
                   smem + 4096 + chunk * 512);
    }

    for (int it = 0; it < 12; ++it) {
        const int co = (it & 1) * 8192;
        const int no = 8192 - co;
        __syncthreads();                           // step-it DMA landed + prev reads done
        if (it < 11) {
            const int k1 = (it + 1) * 64;
#pragma unroll
            for (int i = 0; i < 2; i++) {
                const int chunk = wave * 2 + i;
                async_cp16(A + (long)(m0 + chunk * 8 + lrow) * D_ + k1 + lcg * 8,
                           smem + no + chunk * 512);
                async_cp16(Wsw + (long)(n0 + chunk * 8 + lrow) * D_ + k1 + lcg * 8,
                           smem + no + 4096 + chunk * 512);
            }
        }
        const unsigned short* As = smem + co;
        const unsigned short* Bs = smem + co + 4096;
#pragma unroll
        for (int ks = 0; ks < 2; ks++) {
            const int cg = ks * 4 + quad;
            bf16x8 af[2], bf[2];
#pragma unroll
            for (int s = 0; s < 2; s++) {
                const int r = wm * 32 + s * 16 + l16;
                af[s] = *(const bf16x8*)&As[r * 64 + ((cg ^ (r & 7)) * 8)];
            }
#pragma unroll
            for (int j = 0; j < 2; j++) {
                const int r = wn * 32 + j * 16 + l16;
                bf[j] = *(const bf16x8*)&Bs[r * 64 + ((cg ^ (r & 7)) * 8)];
            }
#pragma unroll
            for (int s = 0; s < 2; s++)
#pragma unroll
                for (int j = 0; j < 2; j++)
                    acc[s][j] = __builtin_amdgcn_mfma_f32_16x16x32_bf16(af[s], bf[j], acc[s][j], 0, 0, 0);
        }
    }

    float bv[2];
#pragma unroll
    for (int j = 0; j < 2; j++) bv[j] = bias[n0 + wn * 32 + j * 16 + l16];

    __syncthreads();                     // done with As/Bs before reuse
    float* fl = (float*)smem;            // [64][67]
#pragma unroll
    for (int s = 0; s < 2; s++)
#pragma unroll
        for (int j = 0; j < 2; j++)
#pragma unroll
            for (int r = 0; r < 4; r++)
                fl[(wm * 32 + s * 16 + quad * 4 + r) * 67 + wn * 32 + j * 16 + l16] =
                    acc[s][j][r] + bv[j];
    __syncthreads();
    const int row = t >> 2, c0 = (t & 3) * 16;
#pragma unroll
    for (int i = 0; i < 4; i++) {
        const float4 v = *(const float4*)&fl[row * 67 + c0 + i * 4];
        *(float4*)(Out + (long)(m0 + row) * D_ + n0 + c0 + i * 4) = v;
    }
}

extern "C" void kernel_launch(void* const* d_in, const int* in_sizes, int n_in,
                              void* d_out, int out_size, void* d_ws, size_t ws_size,
                              hipStream_t stream) {
    const float* k_in = (const float*)d_in[0];
    const float* q_in = (const float*)d_in[1];
    const float* v_in = (const float*)d_in[2];
    // d_in[3] = mask: no-op per reference
    const float* wq = (const float*)d_in[4];
    const float* bq = (const float*)d_in[5];
    const float* wk = (const float*)d_in[6];
    const float* bk = (const float*)d_in[7];
    const float* wv = (const float*)d_in[8];
    const float* bv = (const float*)d_in[9];
    const float* wo = (const float*)d_in[10];
    const float* bo = (const float*)d_in[11];

    unsigned short* ws = (unsigned short*)d_ws;
    unsigned short* Wsw = ws;                          // 4*NW bf16 swizzled
    unsigned short* Qb  = Wsw + 4ll * NW_;             // NX bf16
    unsigned short* Kb  = Qb + (long)NX_;
    unsigned short* Vt  = Kb + (long)NX_;
    unsigned short* Xsw = Vt + (long)NX_;              // 3*NX (dead after qkv)
    unsigned short* Ao  = Xsw;                         // aliases Xsw

    CvtArgs ca;
    ca.s[0] = q_in; ca.s[1] = k_in; ca.s[2] = v_in;
    ca.s[3] = wq;   ca.s[4] = wk;   ca.s[5] = wv;  ca.s[6] = wo;
    cvt_all<<<dim3(2880), 256, 0, stream>>>(ca, Xsw, Wsw);

    QkvArgs qa;
    qa.bias[0] = bq; qa.bias[1] = bk; qa.bias[2] = bv;
    qa.out[0] = Qb;  qa.out[1] = Kb;  qa.out[2] = Vt;
    gemm_qkv<<<dim3(32, 36), 256, 0, stream>>>(qa, Xsw, Wsw);

    attn_kernel<<<dim3(768), 256, 0, stream>>>(Qb, Kb, Vt, Ao);

    gemm_out<<<dim3(64, 12), 256, 0, stream>>>(Ao, Wsw + 3ll * NW_, bo, (float*)d_out);
}